// Round 16
// baseline (783.486 us; speedup 1.0000x reference)
//
#include <hip/hip_runtime.h>
#include <hip/hip_bf16.h>

#define N_ATOMS 30000
#define M_NBR   12

typedef __bf16 bf16x8 __attribute__((ext_vector_type(8)));
typedef float  f32x4  __attribute__((ext_vector_type(4)));

// async global->LDS, 16B per lane: LDS dest = wave-uniform base + lane*16
#define GLOAD_LDS16(g, l) __builtin_amdgcn_global_load_lds( \
    (const __attribute__((address_space(1))) unsigned int*)(const void*)(g), \
    (__attribute__((address_space(3))) unsigned int*)(void*)(l), 16, 0, 0)

__device__ __forceinline__ unsigned pkbf(float a, float b) {
    union { __bf16 h[2]; unsigned u; } r;
    r.h[0] = (__bf16)a; r.h[1] = (__bf16)b;
    return r.u;
}
__device__ __forceinline__ unsigned short f2bf(float f) {
    union { __bf16 h; unsigned short s; } r; r.h = (__bf16)f; return r.s;
}
__device__ __forceinline__ float bflo(unsigned u) { union { unsigned x; float f; } v; v.x = u << 16;          return v.f; }
__device__ __forceinline__ float bfhi(unsigned u) { union { unsigned x; float f; } v; v.x = u & 0xffff0000u;  return v.f; }

__device__ __forceinline__ float fexp2(float x) { return __builtin_amdgcn_exp2f(x); }
__device__ __forceinline__ float flog2(float x) { return __builtin_amdgcn_logf(x); }

__device__ __forceinline__ float rowsum16(float x) {
    union { float f; int i; } a, b;
    a.f = x;
    b.i = __builtin_amdgcn_update_dpp(0, a.i, 0x121, 0xF, 0xF, true); a.f += b.f; // row_ror:1
    b.i = __builtin_amdgcn_update_dpp(0, a.i, 0x122, 0xF, 0xF, true); a.f += b.f; // row_ror:2
    b.i = __builtin_amdgcn_update_dpp(0, a.i, 0x124, 0xF, 0xF, true); a.f += b.f; // row_ror:4
    b.i = __builtin_amdgcn_update_dpp(0, a.i, 0x128, 0xF, 0xF, true); a.f += b.f; // row_ror:8
    return a.f;
}

// packed per-row address for z-column c (0..511): [band:8][l15:16][slot:4]
__device__ __forceinline__ int packAddr8(int c) {
    int cc = c & 255;
    int slot = ((cc >> 4) & 1) + ((c >> 8) << 1);
    return (cc >> 5) * 64 + (cc & 15) * 4 + slot;
}

// ---------------- Kernel 0: pack fc_w into bf16 fragment-order tables ----------
__global__ void pack_weights(const float* __restrict__ fc_w,
                             unsigned short* __restrict__ Wp1,
                             unsigned short* __restrict__ Wp3) {
    int idx = blockIdx.x * 256 + threadIdx.x;
    const int n1 = 32 * 1024 * 8;
    if (idx < n1) {
        int j = idx & 7, n = (idx >> 3) & 1023, g = idx >> 13;
        float v = (n < 512) ? fc_w[n * 640 + g * 8 + j]
                            : fc_w[(n - 512) * 640 + 256 + g * 8 + j];
        Wp1[idx] = f2bf(v);
    } else {
        int k = idx - n1;
        if (k < 16 * 512 * 8) {
            int j = k & 7, n = (k >> 3) & 511, g = k >> 12;
            Wp3[k] = f2bf(fc_w[n * 640 + 512 + g * 8 + j]);
        }
    }
}

// ---------------- Kernel 1: P1 = W1*atom + b, P2 = W2*atom, stored PACKED (bf16) ---
__global__ __launch_bounds__(512, 2) void gemm_p(
    const float* __restrict__ atom, const float* __restrict__ fc_b,
    const unsigned short* __restrict__ Wp1, unsigned short* __restrict__ P)
{
    __shared__ unsigned short sA[128 * 256];
    const int tid = threadIdx.x;
    const int r0 = blockIdx.x * 128;
    const int cb = blockIdx.y;

    #pragma unroll
    for (int s = 0; s < 8; ++s) {
        int G = tid + s * 512;
        int row = G >> 5, gc = G & 31;
        int grow = r0 + row;
        uint4 pk;
        if (grow < N_ATOMS) {
            const float4* src = reinterpret_cast<const float4*>(atom + (size_t)grow * 256 + gc * 8);
            float4 v0 = src[0], v1 = src[1];
            pk.x = pkbf(v0.x, v0.y); pk.y = pkbf(v0.z, v0.w);
            pk.z = pkbf(v1.x, v1.y); pk.w = pkbf(v1.z, v1.w);
        } else {
            pk = make_uint4(0u, 0u, 0u, 0u);
        }
        *reinterpret_cast<uint4*>(&sA[row * 256 + ((gc ^ (row & 7)) << 3)]) = pk;
    }
    __syncthreads();

    const int lane = tid & 63, wave = tid >> 6;
    const int wr = wave >> 2, wcc = wave & 3;
    const int l15 = lane & 15, l16 = lane >> 4;

    f32x4 acc[4][8];
    #pragma unroll
    for (int mt = 0; mt < 4; ++mt)
        #pragma unroll
        for (int nt = 0; nt < 8; ++nt) acc[mt][nt] = f32x4{0.f, 0.f, 0.f, 0.f};

    #pragma unroll
    for (int ks = 0; ks < 8; ++ks) {
        bf16x8 af[4];
        #pragma unroll
        for (int mt = 0; mt < 4; ++mt) {
            int row = wr * 64 + mt * 16 + l15;
            int g = ks * 4 + l16;
            af[mt] = *reinterpret_cast<const bf16x8*>(&sA[row * 256 + ((g ^ (row & 7)) << 3)]);
        }
        bf16x8 bfr[8];
        #pragma unroll
        for (int nt = 0; nt < 8; ++nt) {
            int col = cb * 512 + wcc * 128 + nt * 16 + l15;
            bfr[nt] = *reinterpret_cast<const bf16x8*>(&Wp1[((size_t)(ks * 4 + l16) * 1024 + col) * 8]);
        }
        #pragma unroll
        for (int mt = 0; mt < 4; ++mt)
            #pragma unroll
            for (int nt = 0; nt < 8; ++nt)
                acc[mt][nt] = __builtin_amdgcn_mfma_f32_16x16x32_bf16(af[mt], bfr[nt], acc[mt][nt], 0, 0, 0);
    }

    #pragma unroll
    for (int np = 0; np < 4; ++np) {
        int zc0 = wcc * 128 + np * 32 + l15;
        float b0 = (cb == 0) ? fc_b[zc0] : 0.f;
        float b1 = (cb == 0) ? fc_b[zc0 + 16] : 0.f;
        int pa = cb * 512 + packAddr8(zc0);
        #pragma unroll
        for (int mt = 0; mt < 4; ++mt) {
            #pragma unroll
            for (int j = 0; j < 4; ++j) {
                int row = r0 + wr * 64 + mt * 16 + l16 * 4 + j;
                if (row < N_ATOMS)
                    *reinterpret_cast<unsigned*>(&P[(size_t)row * 1024 + pa]) =
                        pkbf(acc[mt][2 * np][j] + b0, acc[mt][2 * np + 1][j] + b1);
            }
        }
    }
}

// ---------------- Kernel 2: 256 thr / 4 waves / 2 atoms per tile / 4 tiles per block ------
// Row map per tile (as r14): zrow = mt*16 + l16*4 + j; rows 0..23 real, 24..31 pad.
// sP rows 0..23 = P2 halves of nbr[i0*12 + r]; rows 24,25 = P1 halves of atoms i0, i0+1.
// All P rows arrive via global_load_lds (zero VGPR); tile k+1 prefetched under tile k.
#define SP_STRIDE 1040
__global__ __launch_bounds__(256, 4) void fused_conv(
    const float* __restrict__ atom, const float* __restrict__ bond,
    const int* __restrict__ nbr, const unsigned short* __restrict__ P,
    const unsigned short* __restrict__ Wp3,
    const float* __restrict__ ln1_g, const float* __restrict__ ln1_b,
    const float* __restrict__ ln2_g, const float* __restrict__ ln2_b,
    float* __restrict__ out)
{
    __shared__ unsigned short sA[32 * 128];                 // 8KB bond tile (bf16, swizzled)
    __shared__ __align__(16) unsigned char sP[26 * SP_STRIDE];  // 26.5KB P rows
    __shared__ __align__(16) float sRed[2][32][4];          // LN1 wave partials
    __shared__ __align__(16) float sL2[2][2][4];            // [atom][s|q][wave]

    const int tid = threadIdx.x;
    const int i00 = blockIdx.x * 8;                         // 3750 blocks x 4 tiles x 2 atoms
    const int lane = tid & 63, wc = tid >> 6;
    const int l15 = lane & 15, l16 = lane >> 4;
    const float L2E = 1.4426950408889634f;
    const char* Pb = reinterpret_cast<const char*>(P);
    const unsigned cOffA = (unsigned)(wc * 256 + l15 * 8);
    const unsigned cOffB = cOffA + 128u;
    const unsigned lane16 = (unsigned)lane * 16u;

    // LN1 affine params: loaded once, shared by all tiles (16 regs, live whole kernel)
    float g1[4], gC[4], l2b1[4], l2bC[4];
    #pragma unroll
    for (int np = 0; np < 2; ++np)
        #pragma unroll
        for (int b = 0; b < 2; ++b) {
            int nt = np * 2 + b;
            int a = wc * 64 + np * 32 + b * 16 + l15;
            g1[nt] = ln1_g[a];       l2b1[nt] = ln1_b[a] * L2E;
            gC[nt] = ln1_g[256 + a]; l2bC[nt] = ln1_b[256 + a] * L2E;
        }

    // zero sA pad rows 24..31 (once; bond writes touch only rows 0..23)
    *reinterpret_cast<unsigned*>(&sA[3072 + tid * 4]) = 0u;
    *reinterpret_cast<unsigned*>(&sA[3072 + 1024 + (tid & 63) * 4]) = 0u;   // last 128B chunk? (3072..4095 = 1024 shorts)

    // ---- prologue: tile0 P-rows DMA + bond0 ----
    {
        int ib = i00 * 12;
        #pragma unroll
        for (int k = 0; k < 6; ++k) {
            int r = wc + k * 4;                             // rows 0..23
            int nb = nbr[ib + r];
            GLOAD_LDS16(Pb + (unsigned)nb * 2048u + 1024u + lane16, &sP[r * SP_STRIDE]);
        }
        if (wc < 2)
            GLOAD_LDS16(Pb + (unsigned)(i00 + wc) * 2048u + lane16, &sP[(24 + wc) * SP_STRIDE]);
    }
    float4 bv[3];
    #pragma unroll
    for (int s = 0; s < 3; ++s) {
        int g = tid + s * 256;
        int row = g >> 5, gc = g & 31;
        bv[s] = *reinterpret_cast<const float4*>(bond + (size_t)(i00 * 12 + row) * 128 + gc * 4);
    }
    #pragma unroll
    for (int s = 0; s < 3; ++s) {
        int g = tid + s * 256;
        int row = g >> 5, gc = g & 31;
        uint2 pk;
        pk.x = pkbf(bv[s].x, bv[s].y); pk.y = pkbf(bv[s].z, bv[s].w);
        int elem = (((gc >> 1) ^ (row & 7)) << 3) + ((gc & 1) << 2);
        *reinterpret_cast<uint2*>(&sA[row * 128 + elem]) = pk;
    }
    __syncthreads();                                        // B0: sP + sA ready (drains DMA)

    for (int t = 0; t < 4; ++t) {
        const int i0 = i00 + t * 2;

        // ---- acc := P1 + P2 from LDS ----
        f32x4 acc[2][8];
        #pragma unroll
        for (int mt = 0; mt < 2; ++mt) {
            // P1 row for this (mt,l16) group's zrows
            int zr0 = mt * 16 + l16 * 4;
            int p1row = 24 + ((zr0 >= 12) ? 1 : 0);
            uint2 c1A = *reinterpret_cast<const uint2*>(&sP[p1row * SP_STRIDE + cOffA]);
            uint2 c1B = *reinterpret_cast<const uint2*>(&sP[p1row * SP_STRIDE + cOffB]);
            float pg0 = bflo(c1A.x), pg1 = bfhi(c1A.x);
            float pc0 = bflo(c1A.y), pc1 = bfhi(c1A.y);
            float qg0 = bflo(c1B.x), qg1 = bfhi(c1B.x);
            float qc0 = bflo(c1B.y), qc1 = bfhi(c1B.y);
            #pragma unroll
            for (int j = 0; j < 4; ++j) {
                int zrow = zr0 + j;
                int r = (zrow < 24) ? zrow : 23;            // pads read row 23, unused
                uint2 cA = *reinterpret_cast<const uint2*>(&sP[r * SP_STRIDE + cOffA]);
                uint2 cB = *reinterpret_cast<const uint2*>(&sP[r * SP_STRIDE + cOffB]);
                acc[mt][0][j] = pg0 + bflo(cA.x); acc[mt][1][j] = pg1 + bfhi(cA.x);
                acc[mt][4][j] = pc0 + bflo(cA.y); acc[mt][5][j] = pc1 + bfhi(cA.y);
                acc[mt][2][j] = qg0 + bflo(cB.x); acc[mt][3][j] = qg1 + bfhi(cB.x);
                acc[mt][6][j] = qc0 + bflo(cB.y); acc[mt][7][j] = qc1 + bfhi(cB.y);
            }
        }

        // ---- GEMM: acc += [32,128(bond)] @ Wp3 ----
        #pragma unroll
        for (int ks = 0; ks < 4; ++ks) {
            bf16x8 af[2];
            #pragma unroll
            for (int mt = 0; mt < 2; ++mt) {
                int row = mt * 16 + l15;
                af[mt] = *reinterpret_cast<const bf16x8*>(
                    &sA[row * 128 + (((ks * 4 + l16) ^ (row & 7)) << 3)]);
            }
            #pragma unroll
            for (int p = 0; p < 2; ++p)
                #pragma unroll
                for (int np = 0; np < 2; ++np) {
                    int colbase = p * 256 + wc * 64 + np * 32 + l15;
                    bf16x8 b0 = *reinterpret_cast<const bf16x8*>(
                        &Wp3[((size_t)(ks * 4 + l16) * 512 + colbase) * 8]);
                    bf16x8 b1 = *reinterpret_cast<const bf16x8*>(
                        &Wp3[((size_t)(ks * 4 + l16) * 512 + colbase + 16) * 8]);
                    #pragma unroll
                    for (int mt = 0; mt < 2; ++mt) {
                        acc[mt][p * 4 + np * 2 + 0] = __builtin_amdgcn_mfma_f32_16x16x32_bf16(
                            af[mt], b0, acc[mt][p * 4 + np * 2 + 0], 0, 0, 0);
                        acc[mt][p * 4 + np * 2 + 1] = __builtin_amdgcn_mfma_f32_16x16x32_bf16(
                            af[mt], b1, acc[mt][p * 4 + np * 2 + 1], 0, 0, 0);
                    }
                }
        }

        // ---- pass 1: LN1 partial stats ----
        #pragma unroll
        for (int mt = 0; mt < 2; ++mt)
            #pragma unroll
            for (int j = 0; j < 4; ++j) {
                int row = mt * 16 + l16 * 4 + j;
                float s = 0.f, q = 0.f;
                #pragma unroll
                for (int nt = 0; nt < 8; ++nt) {
                    float z = acc[mt][nt][j];
                    s += z; q = fmaf(z, z, q);
                }
                s = rowsum16(s);
                q = rowsum16(q);
                if (l15 == 0) { sRed[0][row][wc] = s; sRed[1][row][wc] = q; }
            }
        __syncthreads();                                    // B_b: sRed ready; sP/sA reads done

        // ---- prefetch tile t+1: bond loads first, then P-row DMAs (stay in flight) ----
        if (t < 3) {
            const int i1 = i0 + 2;
            #pragma unroll
            for (int s = 0; s < 3; ++s) {
                int g = tid + s * 256;
                int row = g >> 5, gc = g & 31;
                bv[s] = *reinterpret_cast<const float4*>(bond + (size_t)(i1 * 12 + row) * 128 + gc * 4);
            }
            int ib = i1 * 12;
            #pragma unroll
            for (int k = 0; k < 6; ++k) {
                int r = wc + k * 4;
                int nb = nbr[ib + r];
                GLOAD_LDS16(Pb + (unsigned)nb * 2048u + 1024u + lane16, &sP[r * SP_STRIDE]);
            }
            if (wc < 2)
                GLOAD_LDS16(Pb + (unsigned)(i1 + wc) * 2048u + lane16, &sP[(24 + wc) * SP_STRIDE]);
        }

        // ---- pass 2: stats fold + sigmoid*softplus (log2 domain) ----
        float pa0[4] = {0.f, 0.f, 0.f, 0.f};
        float pa1[4] = {0.f, 0.f, 0.f, 0.f};
        #pragma unroll
        for (int mt = 0; mt < 2; ++mt) {
            float rs[4], mr[4];
            #pragma unroll
            for (int j = 0; j < 4; ++j) {
                int row = mt * 16 + l16 * 4 + j;
                float4 s4 = *reinterpret_cast<const float4*>(&sRed[0][row][0]);
                float4 q4 = *reinterpret_cast<const float4*>(&sRed[1][row][0]);
                float ssum = (s4.x + s4.y) + (s4.z + s4.w);
                float qsum = (q4.x + q4.y) + (q4.z + q4.w);
                float mu = ssum * (1.f / 512.f);
                float var = qsum * (1.f / 512.f) - mu * mu;
                float r = __builtin_amdgcn_rsqf(var + 1e-5f) * L2E;
                rs[j] = r; mr[j] = mu * r;
            }
            #pragma unroll
            for (int nt = 0; nt < 4; ++nt) {
                float tq = 0.f;
                #pragma unroll
                for (int j = 0; j < 4; ++j) {
                    float ug = fmaf(fmaf(acc[mt][nt][j],     rs[j], -mr[j]), g1[nt], l2b1[nt]);
                    float uc = fmaf(fmaf(acc[mt][nt + 4][j], rs[j], -mr[j]), gC[nt], l2bC[nt]);
                    float gt  = __builtin_amdgcn_rcpf(1.f + fexp2(-ug));
                    float sp2 = flog2(1.f + fexp2(uc));
                    tq = fmaf(gt, sp2, tq);
                }
                if (mt == 0) {
                    if (l16 < 3) pa0[nt] += tq; else pa1[nt] += tq;
                } else {
                    if (l16 < 2) pa1[nt] += tq;
                }
            }
        }
        #pragma unroll
        for (int nt = 0; nt < 4; ++nt) {
            pa0[nt] += __shfl_xor(pa0[nt], 16, 64);
            pa0[nt] += __shfl_xor(pa0[nt], 32, 64);
            pa1[nt] += __shfl_xor(pa1[nt], 16, 64);
            pa1[nt] += __shfl_xor(pa1[nt], 32, 64);
        }

        // ---- stage tile t+1 bond -> sA (waits bond loads; DMAs remain outstanding) ----
        if (t < 3) {
            #pragma unroll
            for (int s = 0; s < 3; ++s) {
                int g = tid + s * 256;
                int row = g >> 5, gc = g & 31;
                uint2 pk;
                pk.x = pkbf(bv[s].x, bv[s].y); pk.y = pkbf(bv[s].z, bv[s].w);
                int elem = (((gc >> 1) ^ (row & 7)) << 3) + ((gc & 1) << 2);
                *reinterpret_cast<uint2*>(&sA[row * 128 + elem]) = pk;
            }
        }

        // ---- LN2 partials ----
        {
            float s0 = (pa0[0] + pa0[1]) + (pa0[2] + pa0[3]);
            float q0 = fmaf(pa0[0], pa0[0], fmaf(pa0[1], pa0[1], fmaf(pa0[2], pa0[2], pa0[3] * pa0[3])));
            float s1 = (pa1[0] + pa1[1]) + (pa1[2] + pa1[3]);
            float q1 = fmaf(pa1[0], pa1[0], fmaf(pa1[1], pa1[1], fmaf(pa1[2], pa1[2], pa1[3] * pa1[3])));
            s0 = rowsum16(s0); q0 = rowsum16(q0);
            s1 = rowsum16(s1); q1 = rowsum16(q1);
            if (lane == 0) {
                sL2[0][0][wc] = s0; sL2[0][1][wc] = q0;
                sL2[1][0][wc] = s1; sL2[1][1][wc] = q1;
            }
        }
        __syncthreads();                                    // B_c: sL2 ready; drains DMAs + sA writes

        // ---- LN2 + residual: l16 group a (0,1) outputs atom i0+a ----
        if (l16 < 2) {
            const int a = l16;
            const int gi = i0 + a;
            float4 sv = *reinterpret_cast<const float4*>(&sL2[a][0][0]);
            float4 qv = *reinterpret_cast<const float4*>(&sL2[a][1][0]);
            float ssum = (sv.x + sv.y) + (sv.z + sv.w);
            float qsum = (qv.x + qv.y) + (qv.z + qv.w);
            float mu = ssum * (1.f / 256.f);
            float var = qsum * (1.f / 256.f) - mu * mu;
            float rstd = __builtin_amdgcn_rsqf(var + 1e-5f);
            #pragma unroll
            for (int np = 0; np < 2; ++np)
                #pragma unroll
                for (int b = 0; b < 2; ++b) {
                    int nt = np * 2 + b;
                    int c = wc * 64 + np * 32 + b * 16 + l15;
                    float vv = (a == 0) ? pa0[nt] : pa1[nt];
                    out[(size_t)gi * 256 + c] = atom[(size_t)gi * 256 + c]
                                              + (vv - mu) * rstd * ln2_g[c] + ln2_b[c];
                }
        }
    }
}

extern "C" void kernel_launch(void* const* d_in, const int* in_sizes, int n_in,
                              void* d_out, int out_size, void* d_ws, size_t ws_size,
                              hipStream_t stream) {
    const float* atom  = (const float*)d_in[0];
    const float* bond  = (const float*)d_in[1];
    const float* fc_w  = (const float*)d_in[2];
    const float* fc_b  = (const float*)d_in[3];
    const float* ln1_g = (const float*)d_in[4];
    const float* ln1_b = (const float*)d_in[5];
    const float* ln2_g = (const float*)d_in[6];
    const float* ln2_b = (const float*)d_in[7];
    const int*   nbr   = (const int*)d_in[8];

    char* ws = (char*)d_ws;
    unsigned short* P   = (unsigned short*)ws;                          // 61,440,000 B
    unsigned short* Wp1 = (unsigned short*)(ws + 61440000);             // 524,288 B
    unsigned short* Wp3 = (unsigned short*)(ws + 61440000 + 524288);    // 131,072 B
    float* outp = (float*)d_out;

    hipLaunchKernelGGL(pack_weights, dim3(1280), dim3(256), 0, stream, fc_w, Wp1, Wp3);
    hipLaunchKernelGGL(gemm_p, dim3(235, 2), dim3(512), 0, stream, atom, fc_b, Wp1, P);
    hipLaunchKernelGGL(fused_conv, dim3(3750), dim3(256), 0, stream,
                       atom, bond, nbr, P, Wp3, ln1_g, ln1_b, ln2_g, ln2_b, outp);
}

// Round 17
// 240.381 us; speedup vs baseline: 3.2594x; 3.2594x over previous
//
#include <hip/hip_runtime.h>
#include <hip/hip_bf16.h>

#define N_ATOMS 30000
#define M_NBR   12

typedef __bf16 bf16x8 __attribute__((ext_vector_type(8)));
typedef float  f32x4  __attribute__((ext_vector_type(4)));

__device__ __forceinline__ unsigned pkbf(float a, float b) {
    union { __bf16 h[2]; unsigned u; } r;
    r.h[0] = (__bf16)a; r.h[1] = (__bf16)b;
    return r.u;
}
__device__ __forceinline__ unsigned short f2bf(float f) {
    union { __bf16 h; unsigned short s; } r; r.h = (__bf16)f; return r.s;
}
__device__ __forceinline__ float bflo(unsigned u) { union { unsigned x; float f; } v; v.x = u << 16;          return v.f; }
__device__ __forceinline__ float bfhi(unsigned u) { union { unsigned x; float f; } v; v.x = u & 0xffff0000u;  return v.f; }

__device__ __forceinline__ float fexp2(float x) { return __builtin_amdgcn_exp2f(x); }
__device__ __forceinline__ float flog2(float x) { return __builtin_amdgcn_logf(x); }

__device__ __forceinline__ float rowsum16(float x) {
    union { float f; int i; } a, b;
    a.f = x;
    b.i = __builtin_amdgcn_update_dpp(0, a.i, 0x121, 0xF, 0xF, true); a.f += b.f; // row_ror:1
    b.i = __builtin_amdgcn_update_dpp(0, a.i, 0x122, 0xF, 0xF, true); a.f += b.f; // row_ror:2
    b.i = __builtin_amdgcn_update_dpp(0, a.i, 0x124, 0xF, 0xF, true); a.f += b.f; // row_ror:4
    b.i = __builtin_amdgcn_update_dpp(0, a.i, 0x128, 0xF, 0xF, true); a.f += b.f; // row_ror:8
    return a.f;
}

// packed per-row address for z-column c (0..511): [band:8][l15:16][slot:4]
// band=(c&255)>>5, slot = bit4(c&255) + 2*(c>=256)
__device__ __forceinline__ int packAddr8(int c) {
    int cc = c & 255;
    int slot = ((cc >> 4) & 1) + ((c >> 8) << 1);
    return (cc >> 5) * 64 + (cc & 15) * 4 + slot;
}

// ---------------- Kernel 0: pack fc_w into bf16 fragment-order tables ----------
__global__ void pack_weights(const float* __restrict__ fc_w,
                             unsigned short* __restrict__ Wp1,
                             unsigned short* __restrict__ Wp3) {
    int idx = blockIdx.x * 256 + threadIdx.x;
    const int n1 = 32 * 1024 * 8;
    if (idx < n1) {
        int j = idx & 7, n = (idx >> 3) & 1023, g = idx >> 13;
        float v = (n < 512) ? fc_w[n * 640 + g * 8 + j]
                            : fc_w[(n - 512) * 640 + 256 + g * 8 + j];
        Wp1[idx] = f2bf(v);
    } else {
        int k = idx - n1;
        if (k < 16 * 512 * 8) {
            int j = k & 7, n = (k >> 3) & 511, g = k >> 12;
            Wp3[k] = f2bf(fc_w[n * 640 + 512 + g * 8 + j]);
        }
    }
}

// ---------------- Kernel 1: P1 = W1*atom + b, P2 = W2*atom, stored PACKED (bf16) ---
__global__ __launch_bounds__(512, 2) void gemm_p(
    const float* __restrict__ atom, const float* __restrict__ fc_b,
    const unsigned short* __restrict__ Wp1, unsigned short* __restrict__ P)
{
    __shared__ unsigned short sA[128 * 256];
    const int tid = threadIdx.x;
    const int r0 = blockIdx.x * 128;
    const int cb = blockIdx.y;

    #pragma unroll
    for (int s = 0; s < 8; ++s) {
        int G = tid + s * 512;
        int row = G >> 5, gc = G & 31;
        int grow = r0 + row;
        uint4 pk;
        if (grow < N_ATOMS) {
            const float4* src = reinterpret_cast<const float4*>(atom + (size_t)grow * 256 + gc * 8);
            float4 v0 = src[0], v1 = src[1];
            pk.x = pkbf(v0.x, v0.y); pk.y = pkbf(v0.z, v0.w);
            pk.z = pkbf(v1.x, v1.y); pk.w = pkbf(v1.z, v1.w);
        } else {
            pk = make_uint4(0u, 0u, 0u, 0u);
        }
        *reinterpret_cast<uint4*>(&sA[row * 256 + ((gc ^ (row & 7)) << 3)]) = pk;
    }
    __syncthreads();

    const int lane = tid & 63, wave = tid >> 6;
    const int wr = wave >> 2, wcc = wave & 3;
    const int l15 = lane & 15, l16 = lane >> 4;

    f32x4 acc[4][8];
    #pragma unroll
    for (int mt = 0; mt < 4; ++mt)
        #pragma unroll
        for (int nt = 0; nt < 8; ++nt) acc[mt][nt] = f32x4{0.f, 0.f, 0.f, 0.f};

    #pragma unroll
    for (int ks = 0; ks < 8; ++ks) {
        bf16x8 af[4];
        #pragma unroll
        for (int mt = 0; mt < 4; ++mt) {
            int row = wr * 64 + mt * 16 + l15;
            int g = ks * 4 + l16;
            af[mt] = *reinterpret_cast<const bf16x8*>(&sA[row * 256 + ((g ^ (row & 7)) << 3)]);
        }
        bf16x8 bfr[8];
        #pragma unroll
        for (int nt = 0; nt < 8; ++nt) {
            int col = cb * 512 + wcc * 128 + nt * 16 + l15;
            bfr[nt] = *reinterpret_cast<const bf16x8*>(&Wp1[((size_t)(ks * 4 + l16) * 1024 + col) * 8]);
        }
        #pragma unroll
        for (int mt = 0; mt < 4; ++mt)
            #pragma unroll
            for (int nt = 0; nt < 8; ++nt)
                acc[mt][nt] = __builtin_amdgcn_mfma_f32_16x16x32_bf16(af[mt], bfr[nt], acc[mt][nt], 0, 0, 0);
    }

    #pragma unroll
    for (int np = 0; np < 4; ++np) {
        int zc0 = wcc * 128 + np * 32 + l15;
        float b0 = (cb == 0) ? fc_b[zc0] : 0.f;
        float b1 = (cb == 0) ? fc_b[zc0 + 16] : 0.f;
        int pa = cb * 512 + packAddr8(zc0);
        #pragma unroll
        for (int mt = 0; mt < 4; ++mt) {
            #pragma unroll
            for (int j = 0; j < 4; ++j) {
                int row = r0 + wr * 64 + mt * 16 + l16 * 4 + j;
                if (row < N_ATOMS)
                    *reinterpret_cast<unsigned*>(&P[(size_t)row * 1024 + pa]) =
                        pkbf(acc[mt][2 * np][j] + b0, acc[mt][2 * np + 1][j] + b1);
            }
        }
    }
}

// ---------------- Kernel 2: 256 threads / 4 waves / 2 atoms per block --------------
// Rows 0..23 real (2 atoms x 12), 24..31 zero-padded. Wave wc owns 64 gate + 64 core cols.
// acc[2][8] = 64 regs -> 4 blocks/CU co-resident = 4 independent barrier streams.
// setprio(1) around the MFMA cluster: with 4 independent streams per CU at different
// phases, GEMM-phase waves win issue arbitration (T5 regime).
__global__ __launch_bounds__(256, 4) void fused_conv(
    const float* __restrict__ atom, const float* __restrict__ bond,
    const int* __restrict__ nbr, const unsigned short* __restrict__ P,
    const unsigned short* __restrict__ Wp3,
    const float* __restrict__ ln1_g, const float* __restrict__ ln1_b,
    const float* __restrict__ ln2_g, const float* __restrict__ ln2_b,
    float* __restrict__ out)
{
    __shared__ unsigned short sA[32 * 128];             // 8KB bond tile (bf16, swizzled)
    __shared__ __align__(16) float sRed[2][32][4];      // LN1 wave partials
    __shared__ __align__(16) float sL2[2][2][4];        // [atom][s|q][wave] LN2 partials

    const int tid = threadIdx.x;
    const int i0 = blockIdx.x * 2;                      // 15000 blocks exact
    const int lane = tid & 63, wc = tid >> 6;           // wc 0..3
    const int l15 = lane & 15, l16 = lane >> 4;
    const float L2E = 1.4426950408889634f;
    const char* Pb = reinterpret_cast<const char*>(P);
    const unsigned cOffA = (unsigned)(wc * 256 + l15 * 8);   // band 2wc
    const unsigned cOffB = cOffA + 128u;                     // band 2wc+1

    // ---- 1) bond loads (24 real rows): 768 granules of 4 floats, 3/thread ----
    float4 bv[3];
    #pragma unroll
    for (int s = 0; s < 3; ++s) {
        int g = tid + s * 256;
        int row = g >> 5, gc = g & 31;
        bv[s] = *reinterpret_cast<const float4*>(bond + (size_t)(i0 * 12 + row) * 128 + gc * 4);
    }

    // ---- 2) nbr + P2/P1 gathers (rows: mt0 = l16*4+j; mt1 = 16+l16*4+j, real only l16<2) ----
    int4 nbq0 = *reinterpret_cast<const int4*>(&nbr[i0 * 12 + l16 * 4]);
    int off16 = (l16 < 2) ? (16 + l16 * 4) : 20;        // clamped, always in-bounds
    int4 nbq1 = *reinterpret_cast<const int4*>(&nbr[i0 * 12 + off16]);

    uint2 p2q[2][4][2];
    {
        const int* n0 = reinterpret_cast<const int*>(&nbq0);
        const int* n1 = reinterpret_cast<const int*>(&nbq1);
        #pragma unroll
        for (int j = 0; j < 4; ++j) {
            unsigned b0 = (unsigned)n0[j] * 2048u + 1024u;
            p2q[0][j][0] = *reinterpret_cast<const uint2*>(Pb + b0 + cOffA);
            p2q[0][j][1] = *reinterpret_cast<const uint2*>(Pb + b0 + cOffB);
            unsigned b1 = (unsigned)n1[j] * 2048u + 1024u;
            p2q[1][j][0] = *reinterpret_cast<const uint2*>(Pb + b1 + cOffA);
            p2q[1][j][1] = *reinterpret_cast<const uint2*>(Pb + b1 + cOffB);
        }
    }
    uint2 p1q[2][2];
    {
        unsigned a0 = (unsigned)(i0 + ((l16 < 3) ? 0 : 1)) * 2048u;   // mt0 atom
        p1q[0][0] = *reinterpret_cast<const uint2*>(Pb + a0 + cOffA);
        p1q[0][1] = *reinterpret_cast<const uint2*>(Pb + a0 + cOffB);
        unsigned a1 = (unsigned)(i0 + 1) * 2048u;                     // mt1 atom (real rows)
        p1q[1][0] = *reinterpret_cast<const uint2*>(Pb + a1 + cOffA);
        p1q[1][1] = *reinterpret_cast<const uint2*>(Pb + a1 + cOffB);
    }

    // ---- 3) stage bond -> LDS (waits bond only); zero pad rows 24..31 ----
    #pragma unroll
    for (int s = 0; s < 3; ++s) {
        int g = tid + s * 256;
        int row = g >> 5, gc = g & 31;
        uint2 pk;
        pk.x = pkbf(bv[s].x, bv[s].y); pk.y = pkbf(bv[s].z, bv[s].w);
        int elem = (((gc >> 1) ^ (row & 7)) << 3) + ((gc & 1) << 2);
        *reinterpret_cast<uint2*>(&sA[row * 128 + elem]) = pk;
    }
    {
        int row = 24 + (tid >> 5), gc = tid & 31;
        *reinterpret_cast<uint2*>(&sA[row * 128 + gc * 4]) = make_uint2(0u, 0u);
    }

    // ---- 4) acc := P1 + P2 (waits gathers; gather regs die before GEMM) ----
    // acc[mt][nt]: nt = p*4 + np*2 + b16 ; cols = p*256 + wc*64 + np*32 + b16*16 + l15
    f32x4 acc[2][8];
    #pragma unroll
    for (int mt = 0; mt < 2; ++mt)
        #pragma unroll
        for (int np = 0; np < 2; ++np) {
            uint2 c1 = p1q[mt][np];
            float pg0 = bflo(c1.x), pg1 = bfhi(c1.x);
            float pc0 = bflo(c1.y), pc1 = bfhi(c1.y);
            #pragma unroll
            for (int j = 0; j < 4; ++j) {
                uint2 c2 = p2q[mt][j][np];
                acc[mt][np * 2 + 0][j]     = pg0 + bflo(c2.x);
                acc[mt][np * 2 + 1][j]     = pg1 + bfhi(c2.x);
                acc[mt][4 + np * 2 + 0][j] = pc0 + bflo(c2.y);
                acc[mt][4 + np * 2 + 1][j] = pc1 + bfhi(c2.y);
            }
        }
    __syncthreads();                                    // B1: sA ready

    // ---- GEMM: acc += [32,128(bond)] @ Wp3 ----
    __builtin_amdgcn_s_setprio(1);
    #pragma unroll
    for (int ks = 0; ks < 4; ++ks) {
        bf16x8 af[2];
        #pragma unroll
        for (int mt = 0; mt < 2; ++mt) {
            int row = mt * 16 + l15;
            af[mt] = *reinterpret_cast<const bf16x8*>(
                &sA[row * 128 + (((ks * 4 + l16) ^ (row & 7)) << 3)]);
        }
        #pragma unroll
        for (int p = 0; p < 2; ++p)
            #pragma unroll
            for (int np = 0; np < 2; ++np) {
                int colbase = p * 256 + wc * 64 + np * 32 + l15;
                bf16x8 b0 = *reinterpret_cast<const bf16x8*>(
                    &Wp3[((size_t)(ks * 4 + l16) * 512 + colbase) * 8]);
                bf16x8 b1 = *reinterpret_cast<const bf16x8*>(
                    &Wp3[((size_t)(ks * 4 + l16) * 512 + colbase + 16) * 8]);
                #pragma unroll
                for (int mt = 0; mt < 2; ++mt) {
                    acc[mt][p * 4 + np * 2 + 0] = __builtin_amdgcn_mfma_f32_16x16x32_bf16(
                        af[mt], b0, acc[mt][p * 4 + np * 2 + 0], 0, 0, 0);
                    acc[mt][p * 4 + np * 2 + 1] = __builtin_amdgcn_mfma_f32_16x16x32_bf16(
                        af[mt], b1, acc[mt][p * 4 + np * 2 + 1], 0, 0, 0);
                }
            }
    }
    __builtin_amdgcn_s_setprio(0);

    // ---- pass 1: LN1 partial stats per row (pads produce unused garbage) ----
    #pragma unroll
    for (int mt = 0; mt < 2; ++mt)
        #pragma unroll
        for (int j = 0; j < 4; ++j) {
            int row = mt * 16 + l16 * 4 + j;
            float s = 0.f, q = 0.f;
            #pragma unroll
            for (int nt = 0; nt < 8; ++nt) {
                float z = acc[mt][nt][j];
                s += z; q = fmaf(z, z, q);
            }
            s = rowsum16(s);
            q = rowsum16(q);
            if (l15 == 0) { sRed[0][row][wc] = s; sRed[1][row][wc] = q; }
        }

    // LN1 affine params (log2e-folded biases); latency hides under barrier
    float g1[4], gC[4], l2b1[4], l2bC[4];
    #pragma unroll
    for (int np = 0; np < 2; ++np)
        #pragma unroll
        for (int b = 0; b < 2; ++b) {
            int nt = np * 2 + b;
            int a = wc * 64 + np * 32 + b * 16 + l15;
            g1[nt] = ln1_g[a];       l2b1[nt] = ln1_b[a] * L2E;
            gC[nt] = ln1_g[256 + a]; l2bC[nt] = ln1_b[256 + a] * L2E;
        }
    __syncthreads();                                    // B2: sRed ready

    // ---- pass 2: per-thread stats fold + sigmoid*softplus + l16-butterfly mean ----
    float pa0[4] = {0.f, 0.f, 0.f, 0.f};
    float pa1[4] = {0.f, 0.f, 0.f, 0.f};
    #pragma unroll
    for (int mt = 0; mt < 2; ++mt) {
        float rs[4], mr[4];
        #pragma unroll
        for (int j = 0; j < 4; ++j) {
            int row = mt * 16 + l16 * 4 + j;
            float4 s4 = *reinterpret_cast<const float4*>(&sRed[0][row][0]);
            float4 q4 = *reinterpret_cast<const float4*>(&sRed[1][row][0]);
            float ssum = (s4.x + s4.y) + (s4.z + s4.w);
            float qsum = (q4.x + q4.y) + (q4.z + q4.w);
            float mu = ssum * (1.f / 512.f);
            float var = qsum * (1.f / 512.f) - mu * mu;
            float r = __builtin_amdgcn_rsqf(var + 1e-5f) * L2E;
            rs[j] = r; mr[j] = mu * r;
        }
        #pragma unroll
        for (int nt = 0; nt < 4; ++nt) {
            float tq = 0.f;
            #pragma unroll
            for (int j = 0; j < 4; ++j) {
                float ug = fmaf(fmaf(acc[mt][nt][j],     rs[j], -mr[j]), g1[nt], l2b1[nt]);
                float uc = fmaf(fmaf(acc[mt][nt + 4][j], rs[j], -mr[j]), gC[nt], l2bC[nt]);
                float gt  = __builtin_amdgcn_rcpf(1.f + fexp2(-ug));
                float sp2 = flog2(1.f + fexp2(uc));
                tq = fmaf(gt, sp2, tq);
            }
            if (mt == 0) {
                if (l16 < 3) pa0[nt] += tq; else pa1[nt] += tq;
            } else {
                if (l16 < 2) pa1[nt] += tq;
            }
        }
    }
    #pragma unroll
    for (int nt = 0; nt < 4; ++nt) {                    // sum the 3 contributors across l16
        pa0[nt] += __shfl_xor(pa0[nt], 16, 64);
        pa0[nt] += __shfl_xor(pa0[nt], 32, 64);
        pa1[nt] += __shfl_xor(pa1[nt], 16, 64);
        pa1[nt] += __shfl_xor(pa1[nt], 32, 64);
    }

    // ---- LN2 partials over this wave's 64 output cols (scale-invariant: no /12, no ln2) ----
    {
        float s0 = (pa0[0] + pa0[1]) + (pa0[2] + pa0[3]);
        float q0 = fmaf(pa0[0], pa0[0], fmaf(pa0[1], pa0[1], fmaf(pa0[2], pa0[2], pa0[3] * pa0[3])));
        float s1 = (pa1[0] + pa1[1]) + (pa1[2] + pa1[3]);
        float q1 = fmaf(pa1[0], pa1[0], fmaf(pa1[1], pa1[1], fmaf(pa1[2], pa1[2], pa1[3] * pa1[3])));
        s0 = rowsum16(s0); q0 = rowsum16(q0);
        s1 = rowsum16(s1); q1 = rowsum16(q1);
        if (lane == 0) {
            sL2[0][0][wc] = s0; sL2[0][1][wc] = q0;
            sL2[1][0][wc] = s1; sL2[1][1][wc] = q1;
        }
    }
    __syncthreads();                                    // B3: sL2 ready

    // ---- LN2 + residual: l16 group a (0,1) outputs atom a ----
    if (l16 < 2) {
        const int a = l16;
        const int gi = i0 + a;
        float4 sv = *reinterpret_cast<const float4*>(&sL2[a][0][0]);
        float4 qv = *reinterpret_cast<const float4*>(&sL2[a][1][0]);
        float ssum = (sv.x + sv.y) + (sv.z + sv.w);
        float qsum = (qv.x + qv.y) + (qv.z + qv.w);
        float mu = ssum * (1.f / 256.f);
        float var = qsum * (1.f / 256.f) - mu * mu;
        float rstd = __builtin_amdgcn_rsqf(var + 1e-5f);
        float vv[4];
        #pragma unroll
        for (int nt = 0; nt < 4; ++nt) vv[nt] = (l16 == 0) ? pa0[nt] : pa1[nt];
        #pragma unroll
        for (int np = 0; np < 2; ++np)
            #pragma unroll
            for (int b = 0; b < 2; ++b) {
                int nt = np * 2 + b;
                int c = wc * 64 + np * 32 + b * 16 + l15;
                out[(size_t)gi * 256 + c] = atom[(size_t)gi * 256 + c]
                                          + (vv[nt] - mu) * rstd * ln2_g[c] + ln2_b[c];
            }
    }
}

extern "C" void kernel_launch(void* const* d_in, const int* in_sizes, int n_in,
                              void* d_out, int out_size, void* d_ws, size_t ws_size,
                              hipStream_t stream) {
    const float* atom  = (const float*)d_in[0];
    const float* bond  = (const float*)d_in[1];
    const float* fc_w  = (const float*)d_in[2];
    const float* fc_b  = (const float*)d_in[3];
    const float* ln1_g = (const float*)d_in[4];
    const float* ln1_b = (const float*)d_in[5];
    const float* ln2_g = (const float*)d_in[6];
    const float* ln2_b = (const float*)d_in[7];
    const int*   nbr   = (const int*)d_in[8];

    char* ws = (char*)d_ws;
    unsigned short* P   = (unsigned short*)ws;                          // 61,440,000 B
    unsigned short* Wp1 = (unsigned short*)(ws + 61440000);             // 524,288 B
    unsigned short* Wp3 = (unsigned short*)(ws + 61440000 + 524288);    // 131,072 B
    float* outp = (float*)d_out;

    hipLaunchKernelGGL(pack_weights, dim3(1280), dim3(256), 0, stream, fc_w, Wp1, Wp3);
    hipLaunchKernelGGL(gemm_p, dim3(235, 2), dim3(512), 0, stream, atom, fc_b, Wp1, P);
    hipLaunchKernelGGL(fused_conv, dim3(15000), dim3(256), 0, stream,
                       atom, bond, nbr, P, Wp3, ln1_g, ln1_b, ln2_g, ln2_b, outp);
}